// Round 3
// baseline (3231.144 us; speedup 1.0000x reference)
//
#include <hip/hip_runtime.h>
#include <math.h>

// ---------------------------------------------------------------------------
// EncoderLayer: B=8192, C=12, D=64.
// K1 : mamba block. lane = e (0..63); one wave = 8 b-rows of one c.
//      Weight rows hoisted to registers; activations in per-wave LDS slabs
//      (runtime-indexable -> small code, rolled loops). -> all_out in d_out.
// K23: per-b fused transformer over C (4 heads, S=64, E=12) then over D
//      (8 heads, S=12, E=64) -> final out (d_out). No d_ws use.
// All f32. Dead paths (x123/dense, A_log, conv_w[...,0]) skipped.
// ---------------------------------------------------------------------------

__device__ __forceinline__ float dot4f(const float4 a, const float4 b) {
    return a.x * b.x + a.y * b.y + a.z * b.z + a.w * b.w;
}
__device__ __forceinline__ float silu_f(float x) { return x / (1.f + __expf(-x)); }
__device__ __forceinline__ float softplus_f(float x) {
    return fmaxf(x, 0.f) + log1pf(__expf(-fabsf(x)));
}
__device__ __forceinline__ float gelu_f(float x) {
    return 0.5f * x * (1.f + erff(x * 0.70710678118654752440f));
}
__device__ __forceinline__ float wave_sum64(float v) {
#pragma unroll
    for (int m = 32; m > 0; m >>= 1) v += __shfl_xor(v, m, 64);
    return v;
}

// ---------------------------------------------------------------------------
// K1: mamba. grid (256, 12), block 256 = 4 waves. Wave w: c = blockIdx.y,
// b-range [ (blockIdx.x*4+w)*8, +8 ). lane = e.
// ---------------------------------------------------------------------------
__global__ __launch_bounds__(256) void k1_mamba(
    const float* __restrict__ x,          // (8192,12,64)
    const float* __restrict__ in_proj_w,  // (12,128,64)
    const float* __restrict__ conv_w,     // (12,64,2)
    const float* __restrict__ conv_b,     // (12,64)
    const float* __restrict__ x_proj_w,   // (12,16,64)
    const float* __restrict__ dt_proj_w,  // (12,64,4)
    const float* __restrict__ dt_proj_b,  // (12,64)
    const float* __restrict__ D_ssm,      // (12,64)
    const float* __restrict__ out_proj_w, // (12,64,64)
    const float* __restrict__ channel_w,  // (12)
    float* __restrict__ s1)               // (8192,12,64) all_out
{
    __shared__ __align__(16) float Xl[4][8][68];  // x rows (residual source)
    __shared__ __align__(16) float Cl[4][8][68];  // xc, then y
    __shared__ __align__(16) float Zl[4][8][68];  // silu(z)
    __shared__ __align__(16) float Pr[4][8][16];  // proj

    const int w  = threadIdx.x >> 6;
    const int l  = threadIdx.x & 63;
    const int c  = blockIdx.y;
    const int b0 = (blockIdx.x * 4 + w) * 8;

    // per-lane channel params (lane l = d index)
    const float cw1  = conv_w[c * 128 + 2 * l + 1];
    const float cbl  = conv_b[c * 64 + l];
    const float4 wdt = *(const float4*)(dt_proj_w + c * 256 + 4 * l);
    const float dtbl = dt_proj_b[c * 64 + l];
    const float dsml = D_ssm[c * 64 + l];
    const float cwc  = channel_w[c];

    const float* Wi = in_proj_w + c * (128 * 64);
    const float* Wp = x_proj_w + c * (16 * 64);
    const float* Wo = out_proj_w + c * (64 * 64);

    // stage x rows (coalesced 256B per row)
    for (int r = 0; r < 8; ++r)
        Xl[w][r][l] = x[((b0 + r) * 12 + c) * 64 + l];
    __syncthreads();

    // pass A: xs,z dots with W rows hoisted to registers; b-loop rolled
    {
        const float4* WiA = (const float4*)(Wi + l * 64);
        const float4* WiB = (const float4*)(Wi + (64 + l) * 64);
        float4 wa[16], wb[16];
#pragma unroll
        for (int i = 0; i < 16; ++i) { wa[i] = WiA[i]; wb[i] = WiB[i]; }
        for (int r = 0; r < 8; ++r) {
            const float4* xr = (const float4*)(&Xl[w][r][0]);
            float a0 = 0.f, a1 = 0.f, z0 = 0.f, z1 = 0.f;
#pragma unroll
            for (int i = 0; i < 16; i += 2) {
                float4 x0 = xr[i], x1 = xr[i + 1];
                a0 += dot4f(x0, wa[i]);
                a1 += dot4f(x1, wa[i + 1]);
                z0 += dot4f(x0, wb[i]);
                z1 += dot4f(x1, wb[i + 1]);
            }
            const float xs = a0 + a1;
            const float z  = z0 + z1;
            Cl[w][r][l] = silu_f(xs * cw1 + cbl);
            Zl[w][r][l] = silu_f(z);
        }
    }
    __syncthreads();

    // proj: 128 (r,f) tasks over 64 lanes (2 per lane)
    {
        const int f = l & 15;
        const float4* wp = (const float4*)(Wp + f * 64);
        float4 wv[16];
#pragma unroll
        for (int i = 0; i < 16; ++i) wv[i] = wp[i];
#pragma unroll
        for (int task = 0; task < 2; ++task) {
            const int r = (l >> 4) + 4 * task;
            const float4* xc4 = (const float4*)(&Cl[w][r][0]);
            float a0 = 0.f, a1 = 0.f;
#pragma unroll
            for (int i = 0; i < 16; i += 2) {
                a0 += dot4f(xc4[i], wv[i]);
                a1 += dot4f(xc4[i + 1], wv[i + 1]);
            }
            Pr[w][r][f] = a0 + a1;
        }
    }
    __syncthreads();

    // y = xc * (dt*bc + D) * silu(z)   (overwrites Cl)
    for (int r = 0; r < 8; ++r) {
        const float* pr = &Pr[w][r][0];
        const float bc = pr[4] * pr[10] + pr[5] * pr[11] + pr[6] * pr[12] +
                         pr[7] * pr[13] + pr[8] * pr[14] + pr[9] * pr[15];
        const float dt = softplus_f(pr[0] * wdt.x + pr[1] * wdt.y +
                                    pr[2] * wdt.z + pr[3] * wdt.w + dtbl);
        Cl[w][r][l] = Cl[w][r][l] * (dt * bc + dsml) * Zl[w][r][l];
    }
    __syncthreads();

    // out-proj + channel weight + residual
    {
        const float4* wo = (const float4*)(Wo + l * 64);
        float4 wv[16];
#pragma unroll
        for (int i = 0; i < 16; ++i) wv[i] = wo[i];
        for (int r = 0; r < 8; ++r) {
            const float4* yr = (const float4*)(&Cl[w][r][0]);
            float a0 = 0.f, a1 = 0.f;
#pragma unroll
            for (int i = 0; i < 16; i += 2) {
                a0 += dot4f(yr[i], wv[i]);
                a1 += dot4f(yr[i + 1], wv[i + 1]);
            }
            s1[((b0 + r) * 12 + c) * 64 + l] = cwc * (a0 + a1) + Xl[w][r][l];
        }
    }
}

// ---------------------------------------------------------------------------
// K23: fused transformer stack. One wave per b (4 waves/block).
// Phase 1 (enc over C): lane = token s (S=64, E=12, 4 heads, hd=3). K,V in
//   LDS (overlaying Q2's region); q/scores/post-attn in registers. Output
//   x2[b][c][l] goes straight into Xs.
// Phase 2 (enc over D): S=12 tokens, E=64, 8 heads, hd=8. Per-lane weight
//   rows in registers; X/QKV/O in padded 16B-aligned LDS; LN(64) via wave
//   shuffle reduction. Writes final output.
// ---------------------------------------------------------------------------
__global__ __launch_bounds__(256) void k23_enc(
    const float* __restrict__ s1,     // (8192,12,64) all_out  (== d_out)
    const float* __restrict__ in_w1,  // (36,12)
    const float* __restrict__ in_b1,  // (36)
    const float* __restrict__ ow1,    // (12,12)
    const float* __restrict__ ob1,    // (12)
    const float* __restrict__ n1g, const float* __restrict__ n1b,  // (12)
    const float* __restrict__ m1w1, const float* __restrict__ m1b1, // (24,12),(24)
    const float* __restrict__ m1w2, const float* __restrict__ m1b2, // (12,24),(12)
    const float* __restrict__ in_w2,  // (192,64)
    const float* __restrict__ in_b2,  // (192)
    const float* __restrict__ ow2,    // (64,64)
    const float* __restrict__ ob2,    // (64)
    const float* __restrict__ n2g, const float* __restrict__ n2b,  // (64)
    const float* __restrict__ m2w1, const float* __restrict__ m2b1, // (128,64),(128)
    const float* __restrict__ m2w2, const float* __restrict__ m2b2, // (64,128),(64)
    float* __restrict__ out)          // (8192,12,64) (== d_out)
{
    __shared__ __align__(16) float Xs[4][12][68];   // 13056 B
    __shared__ __align__(16) float Q2[4][12][193];  // 37056 B (qkv; overlays KV, H)
    __shared__ __align__(16) float O2[4][12][68];   // 13056 B   total 63168 B

    const int w = threadIdx.x >> 6;
    const int l = threadIdx.x & 63;
    const int b = blockIdx.x * 4 + w;

    // ---- Phase 1: encoder over C -----------------------------------------
    float* KVp = &Q2[w][0][0];  // KV[64][25] overlay: [t][ k0..11 | v0..11 ]

    const float* src = s1 + b * (12 * 64);
    float tr[12];
#pragma unroll
    for (int i = 0; i < 12; ++i) tr[i] = src[i * 64 + l];

    float qreg[12];
#pragma unroll
    for (int e = 0; e < 12; ++e) {
        float acc = in_b1[e];
#pragma unroll
        for (int cc = 0; cc < 12; ++cc) acc += tr[cc] * in_w1[e * 12 + cc];
        qreg[e] = acc * 0.57735026918962576451f;  // hd=3 -> 1/sqrt(3)
    }
#pragma unroll
    for (int e = 12; e < 36; ++e) {
        float acc = in_b1[e];
#pragma unroll
        for (int cc = 0; cc < 12; ++cc) acc += tr[cc] * in_w1[e * 12 + cc];
        KVp[l * 25 + (e - 12)] = acc;
    }
    __syncthreads();

    float orow[12];
#pragma unroll
    for (int h = 0; h < 4; ++h) {
        const float q0 = qreg[3 * h + 0], q1 = qreg[3 * h + 1], q2 = qreg[3 * h + 2];
        float sc[64];
        float mx = -1e30f;
#pragma unroll
        for (int t = 0; t < 64; ++t) {
            float s = q0 * KVp[t * 25 + 3 * h + 0] + q1 * KVp[t * 25 + 3 * h + 1] +
                      q2 * KVp[t * 25 + 3 * h + 2];
            sc[t] = s;
            mx = fmaxf(mx, s);
        }
        float sum = 0.f;
#pragma unroll
        for (int t = 0; t < 64; ++t) { float p = __expf(sc[t] - mx); sc[t] = p; sum += p; }
        const float inv = 1.f / sum;
        float o0 = 0.f, o1 = 0.f, o2 = 0.f;
#pragma unroll
        for (int t = 0; t < 64; ++t) {
            const float p = sc[t];
            o0 += p * KVp[t * 25 + 12 + 3 * h + 0];
            o1 += p * KVp[t * 25 + 12 + 3 * h + 1];
            o2 += p * KVp[t * 25 + 12 + 3 * h + 2];
        }
        orow[3 * h + 0] = o0 * inv;
        orow[3 * h + 1] = o1 * inv;
        orow[3 * h + 2] = o2 * inv;
    }

    // out-proj + residual + LN(12)
    float a[12];
#pragma unroll
    for (int cc = 0; cc < 12; ++cc) {
        float acc = ob1[cc];
#pragma unroll
        for (int e = 0; e < 12; ++e) acc += orow[e] * ow1[cc * 12 + e];
        a[cc] = tr[cc] + acc;
    }
    {
        float mu = 0.f;
#pragma unroll
        for (int i = 0; i < 12; ++i) mu += a[i];
        mu *= (1.f / 12.f);
        float var = 0.f;
#pragma unroll
        for (int i = 0; i < 12; ++i) { float d = a[i] - mu; var += d * d; }
        var *= (1.f / 12.f);
        const float rs = rsqrtf(var + 1e-5f);
#pragma unroll
        for (int i = 0; i < 12; ++i) a[i] = (a[i] - mu) * rs * n1g[i] + n1b[i];
    }

    // MLP 12 -> 24 -> 12 (exact gelu), residual
    float a2[12];
#pragma unroll
    for (int i = 0; i < 12; ++i) a2[i] = a[i] + m1b2[i];
#pragma unroll
    for (int k = 0; k < 24; ++k) {
        float acc = m1b1[k];
#pragma unroll
        for (int cc = 0; cc < 12; ++cc) acc += a[cc] * m1w1[k * 12 + cc];
        const float hk = gelu_f(acc);
#pragma unroll
        for (int cc = 0; cc < 12; ++cc) a2[cc] += hk * m1w2[cc * 24 + k];
    }

    // second LN(12) with norm1 params -> x2 row, straight into Xs
    {
        float mu = 0.f;
#pragma unroll
        for (int i = 0; i < 12; ++i) mu += a2[i];
        mu *= (1.f / 12.f);
        float var = 0.f;
#pragma unroll
        for (int i = 0; i < 12; ++i) { float d = a2[i] - mu; var += d * d; }
        var *= (1.f / 12.f);
        const float rs = rsqrtf(var + 1e-5f);
#pragma unroll
        for (int cc = 0; cc < 12; ++cc)
            Xs[w][cc][l] = (a2[cc] - mu) * rs * n1g[cc] + n1b[cc];
    }
    __syncthreads();  // Xs ready; KV region free for Q2 reuse

    // ---- Phase 2: encoder over D -----------------------------------------
    // qkv: lane owns output cols e = k*64 + l; weight row in registers
#pragma unroll
    for (int k = 0; k < 3; ++k) {
        const int e = k * 64 + l;
        const float4* Wrow = (const float4*)(in_w2 + e * 64);
        float4 wv[16];
#pragma unroll
        for (int i = 0; i < 16; ++i) wv[i] = Wrow[i];
        const float bias = in_b2[e];
        const float scale = (k == 0) ? 0.35355339059327376220f : 1.f;  // hd=8
#pragma unroll
        for (int t = 0; t < 12; ++t) {
            const float4* xrow = (const float4*)(&Xs[w][t][0]);
            float a0 = 0.f, a1 = 0.f, a2s = 0.f, a3 = 0.f;
#pragma unroll
            for (int i = 0; i < 16; i += 4) {
                a0  += dot4f(xrow[i + 0], wv[i + 0]);
                a1  += dot4f(xrow[i + 1], wv[i + 1]);
                a2s += dot4f(xrow[i + 2], wv[i + 2]);
                a3  += dot4f(xrow[i + 3], wv[i + 3]);
            }
            Q2[w][t][e] = ((a0 + a1) + (a2s + a3) + bias) * scale;
        }
    }
    __syncthreads();

    // attention: 96 (head,s) rows over 64 lanes
#pragma unroll
    for (int rep = 0; rep < 2; ++rep) {
        const int r = l + rep * 64;
        if (r < 96) {
            const int h = r / 12;
            const int s = r - h * 12;
            float q[8];
#pragma unroll
            for (int d = 0; d < 8; ++d) q[d] = Q2[w][s][h * 8 + d];
            float scv[12];
            float mx = -1e30f;
#pragma unroll
            for (int t = 0; t < 12; ++t) {
                float acc = 0.f;
#pragma unroll
                for (int d = 0; d < 8; ++d) acc += q[d] * Q2[w][t][64 + h * 8 + d];
                scv[t] = acc;
                mx = fmaxf(mx, acc);
            }
            float sum = 0.f;
#pragma unroll
            for (int t = 0; t < 12; ++t) { float p = __expf(scv[t] - mx); scv[t] = p; sum += p; }
            const float inv = 1.f / sum;
#pragma unroll
            for (int d = 0; d < 8; ++d) {
                float o = 0.f;
#pragma unroll
                for (int t = 0; t < 12; ++t) o += scv[t] * Q2[w][t][128 + h * 8 + d];
                O2[w][s][h * 8 + d] = o * inv;
            }
        }
    }
    __syncthreads();

    // out-proj + residual + LN(64, cross-lane); x_att kept in xa[] and Xs
    float xa[12];
    {
        const float4* Wrow = (const float4*)(ow2 + l * 64);
        float4 wv[16];
#pragma unroll
        for (int i = 0; i < 16; ++i) wv[i] = Wrow[i];
        const float bias = ob2[l];
        const float gg = n2g[l], bb = n2b[l];
#pragma unroll
        for (int t = 0; t < 12; ++t) {
            const float4* orow2 = (const float4*)(&O2[w][t][0]);
            float a0 = 0.f, a1 = 0.f, a2s = 0.f, a3 = 0.f;
#pragma unroll
            for (int i = 0; i < 16; i += 4) {
                a0  += dot4f(orow2[i + 0], wv[i + 0]);
                a1  += dot4f(orow2[i + 1], wv[i + 1]);
                a2s += dot4f(orow2[i + 2], wv[i + 2]);
                a3  += dot4f(orow2[i + 3], wv[i + 3]);
            }
            float v = Xs[w][t][l] + (a0 + a1) + (a2s + a3) + bias;
            const float mu = wave_sum64(v) * (1.f / 64.f);
            const float dv = v - mu;
            const float var = wave_sum64(dv * dv) * (1.f / 64.f);
            const float vn = dv * rsqrtf(var + 1e-5f) * gg + bb;
            xa[t] = vn;
            Xs[w][t][l] = vn;
        }
    }
    __syncthreads();

    // MLP hidden 64 -> 128 (exact gelu); H overlays Q2, stride 132 (16B-aligned)
    float* Hb = &Q2[w][0][0];
#pragma unroll
    for (int k = 0; k < 2; ++k) {
        const int kk = k * 64 + l;
        const float4* Wrow = (const float4*)(m2w1 + kk * 64);
        float4 wv[16];
#pragma unroll
        for (int i = 0; i < 16; ++i) wv[i] = Wrow[i];
        const float bias = m2b1[kk];
#pragma unroll
        for (int t = 0; t < 12; ++t) {
            const float4* xrow = (const float4*)(&Xs[w][t][0]);
            float a0 = 0.f, a1 = 0.f, a2s = 0.f, a3 = 0.f;
#pragma unroll
            for (int i = 0; i < 16; i += 4) {
                a0  += dot4f(xrow[i + 0], wv[i + 0]);
                a1  += dot4f(xrow[i + 1], wv[i + 1]);
                a2s += dot4f(xrow[i + 2], wv[i + 2]);
                a3  += dot4f(xrow[i + 3], wv[i + 3]);
            }
            Hb[t * 132 + kk] = gelu_f((a0 + a1) + (a2s + a3) + bias);
        }
    }
    __syncthreads();

    // MLP out 128 -> 64 + residual + final LN(64), write output
    float accf[12];
#pragma unroll
    for (int t = 0; t < 12; ++t) accf[t] = m2b2[l];
#pragma unroll
    for (int k = 0; k < 2; ++k) {
        const float4* Wrow = (const float4*)(m2w2 + l * 128 + k * 64);
        float4 wv[16];
#pragma unroll
        for (int i = 0; i < 16; ++i) wv[i] = Wrow[i];
#pragma unroll
        for (int t = 0; t < 12; ++t) {
            const float4* hrow = (const float4*)(&Hb[t * 132 + k * 64]);
            float a0 = 0.f, a1 = 0.f, a2s = 0.f, a3 = 0.f;
#pragma unroll
            for (int i = 0; i < 16; i += 4) {
                a0  += dot4f(hrow[i + 0], wv[i + 0]);
                a1  += dot4f(hrow[i + 1], wv[i + 1]);
                a2s += dot4f(hrow[i + 2], wv[i + 2]);
                a3  += dot4f(hrow[i + 3], wv[i + 3]);
            }
            accf[t] += (a0 + a1) + (a2s + a3);
        }
    }
    {
        const float gg = n2g[l], bb = n2b[l];
        float* dst = out + b * (12 * 64);
#pragma unroll
        for (int t = 0; t < 12; ++t) {
            float v = xa[t] + accf[t];
            const float mu = wave_sum64(v) * (1.f / 64.f);
            const float dv = v - mu;
            const float var = wave_sum64(dv * dv) * (1.f / 64.f);
            dst[t * 64 + l] = dv * rsqrtf(var + 1e-5f) * gg + bb;
        }
    }
}

// ---------------------------------------------------------------------------
extern "C" void kernel_launch(void* const* d_in, const int* in_sizes, int n_in,
                              void* d_out, int out_size, void* d_ws, size_t ws_size,
                              hipStream_t stream) {
    (void)in_sizes; (void)n_in; (void)d_ws; (void)ws_size; (void)out_size;

    const float* x          = (const float*)d_in[0];
    const float* in_proj_w  = (const float*)d_in[2];
    const float* conv_w     = (const float*)d_in[3];
    const float* conv_b     = (const float*)d_in[4];
    const float* x_proj_w   = (const float*)d_in[5];
    const float* dt_proj_w  = (const float*)d_in[6];
    const float* dt_proj_b  = (const float*)d_in[7];
    const float* D_ssm      = (const float*)d_in[9];
    const float* out_proj_w = (const float*)d_in[10];
    const float* channel_w  = (const float*)d_in[11];
    const float* a1_in_w  = (const float*)d_in[12];
    const float* a1_in_b  = (const float*)d_in[13];
    const float* a1_out_w = (const float*)d_in[14];
    const float* a1_out_b = (const float*)d_in[15];
    const float* a2_in_w  = (const float*)d_in[16];
    const float* a2_in_b  = (const float*)d_in[17];
    const float* a2_out_w = (const float*)d_in[18];
    const float* a2_out_b = (const float*)d_in[19];
    const float* n1g = (const float*)d_in[20];
    const float* n1b = (const float*)d_in[21];
    const float* n2g = (const float*)d_in[22];
    const float* n2b = (const float*)d_in[23];
    const float* m1w1 = (const float*)d_in[24];
    const float* m1b1 = (const float*)d_in[25];
    const float* m1w2 = (const float*)d_in[26];
    const float* m1b2 = (const float*)d_in[27];
    const float* m2w1 = (const float*)d_in[28];
    const float* m2b1 = (const float*)d_in[29];
    const float* m2w2 = (const float*)d_in[30];
    const float* m2b2 = (const float*)d_in[31];

    float* out = (float*)d_out;
    float* s1  = out;  // stage-1 scratch reuses d_out (each wave reads its own
                       // b-slice before K23 overwrites it with the final out)

    k1_mamba<<<dim3(8192 / 32, 12), 256, 0, stream>>>(
        x, in_proj_w, conv_w, conv_b, x_proj_w, dt_proj_w, dt_proj_b,
        D_ssm, out_proj_w, channel_w, s1);

    k23_enc<<<dim3(8192 / 4), 256, 0, stream>>>(
        s1, a1_in_w, a1_in_b, a1_out_w, a1_out_b,
        n1g, n1b, m1w1, m1b1, m1w2, m1b2,
        a2_in_w, a2_in_b, a2_out_w, a2_out_b,
        n2g, n2b, m2w1, m2b1, m2w2, m2b2, out);
}

// Round 4
// 2683.941 us; speedup vs baseline: 1.2039x; 1.2039x over previous
//
#include <hip/hip_runtime.h>
#include <math.h>

// ---------------------------------------------------------------------------
// EncoderLayer: B=8192, C=12, D=64.
// K1: mamba block. lane = e; one wave = 8 b-rows of one c. -> all_out (d_out)
// K2: transformer over C (4 heads, S=64, E=12). In-place on d_out.
//     Two-pass softmax (no sc[64] array) -> no spills.
// K3: transformer over D (8 heads, S=12, E=64). In-place on d_out.
//     O overlays Q cols, H overlays K/V cols -> 50.7KB LDS, 3 blocks/CU.
// All f32. Dead paths (x123/dense, A_log, conv_w[...,0]) skipped.
// Spill discipline: register arrays only with compile-time indices; big
// hoisted weight blocks live in exactly one pass; launch_bounds caps VGPR.
// ---------------------------------------------------------------------------

__device__ __forceinline__ float dot4f(const float4 a, const float4 b) {
    return a.x * b.x + a.y * b.y + a.z * b.z + a.w * b.w;
}
__device__ __forceinline__ float silu_f(float x) { return x / (1.f + __expf(-x)); }
__device__ __forceinline__ float softplus_f(float x) {
    return fmaxf(x, 0.f) + log1pf(__expf(-fabsf(x)));
}
__device__ __forceinline__ float gelu_f(float x) {
    return 0.5f * x * (1.f + erff(x * 0.70710678118654752440f));
}
__device__ __forceinline__ float wave_sum64(float v) {
#pragma unroll
    for (int m = 32; m > 0; m >>= 1) v += __shfl_xor(v, m, 64);
    return v;
}

// ---------------------------------------------------------------------------
// K1: mamba. grid (256, 12), block 256 = 4 waves. Wave w: c = blockIdx.y,
// b-range [(blockIdx.x*4+w)*8, +8). lane = channel e.
// ---------------------------------------------------------------------------
__global__ __launch_bounds__(256, 4) void k1_mamba(
    const float* __restrict__ x,          // (8192,12,64)
    const float* __restrict__ in_proj_w,  // (12,128,64)
    const float* __restrict__ conv_w,     // (12,64,2)
    const float* __restrict__ conv_b,     // (12,64)
    const float* __restrict__ x_proj_w,   // (12,16,64)
    const float* __restrict__ dt_proj_w,  // (12,64,4)
    const float* __restrict__ dt_proj_b,  // (12,64)
    const float* __restrict__ D_ssm,      // (12,64)
    const float* __restrict__ out_proj_w, // (12,64,64)
    const float* __restrict__ channel_w,  // (12)
    float* __restrict__ s1)               // (8192,12,64) all_out
{
    __shared__ __align__(16) float Xl[4][8][68];  // x rows (residual)
    __shared__ __align__(16) float Cl[4][8][68];  // xc, then y
    __shared__ __align__(16) float Zl[4][8][68];  // silu(z)
    __shared__ __align__(16) float Pr[4][8][16];  // proj

    const int w  = threadIdx.x >> 6;
    const int l  = threadIdx.x & 63;
    const int c  = blockIdx.y;
    const int b0 = (blockIdx.x * 4 + w) * 8;

    const float cw1  = conv_w[c * 128 + 2 * l + 1];
    const float cbl  = conv_b[c * 64 + l];
    const float4 wdt = *(const float4*)(dt_proj_w + c * 256 + 4 * l);
    const float dtbl = dt_proj_b[c * 64 + l];
    const float dsml = D_ssm[c * 64 + l];
    const float cwc  = channel_w[c];

    const float* Wi = in_proj_w + c * (128 * 64);
    const float* Wp = x_proj_w + c * (16 * 64);
    const float* Wo = out_proj_w + c * (64 * 64);

    for (int r = 0; r < 8; ++r)
        Xl[w][r][l] = x[((b0 + r) * 12 + c) * 64 + l];
    __syncthreads();

    // pass A1: xs dot (row l of Wi) -> xc
    {
        const float4* WiA = (const float4*)(Wi + l * 64);
        float4 wa[16];
#pragma unroll
        for (int i = 0; i < 16; ++i) wa[i] = WiA[i];
        for (int r = 0; r < 8; ++r) {
            const float4* xr = (const float4*)(&Xl[w][r][0]);
            float a0 = 0.f, a1 = 0.f;
#pragma unroll
            for (int i = 0; i < 16; i += 2) {
                a0 += dot4f(xr[i], wa[i]);
                a1 += dot4f(xr[i + 1], wa[i + 1]);
            }
            Cl[w][r][l] = silu_f((a0 + a1) * cw1 + cbl);
        }
    }
    // pass A2: z dot (row 64+l of Wi) -> silu(z)
    {
        const float4* WiB = (const float4*)(Wi + (64 + l) * 64);
        float4 wb[16];
#pragma unroll
        for (int i = 0; i < 16; ++i) wb[i] = WiB[i];
        for (int r = 0; r < 8; ++r) {
            const float4* xr = (const float4*)(&Xl[w][r][0]);
            float z0 = 0.f, z1 = 0.f;
#pragma unroll
            for (int i = 0; i < 16; i += 2) {
                z0 += dot4f(xr[i], wb[i]);
                z1 += dot4f(xr[i + 1], wb[i + 1]);
            }
            Zl[w][r][l] = silu_f(z0 + z1);
        }
    }
    __syncthreads();

    // proj: 128 (r,f) tasks over 64 lanes (2 per lane)
    {
        const int f = l & 15;
        const float4* wp = (const float4*)(Wp + f * 64);
        float4 wv[16];
#pragma unroll
        for (int i = 0; i < 16; ++i) wv[i] = wp[i];
#pragma unroll
        for (int task = 0; task < 2; ++task) {
            const int r = (l >> 4) + 4 * task;
            const float4* xc4 = (const float4*)(&Cl[w][r][0]);
            float a0 = 0.f, a1 = 0.f;
#pragma unroll
            for (int i = 0; i < 16; i += 2) {
                a0 += dot4f(xc4[i], wv[i]);
                a1 += dot4f(xc4[i + 1], wv[i + 1]);
            }
            Pr[w][r][f] = a0 + a1;
        }
    }
    __syncthreads();

    // y = xc * (dt*bc + D) * silu(z)   (overwrites Cl)
    for (int r = 0; r < 8; ++r) {
        const float* pr = &Pr[w][r][0];
        const float bc = pr[4] * pr[10] + pr[5] * pr[11] + pr[6] * pr[12] +
                         pr[7] * pr[13] + pr[8] * pr[14] + pr[9] * pr[15];
        const float dt = softplus_f(pr[0] * wdt.x + pr[1] * wdt.y +
                                    pr[2] * wdt.z + pr[3] * wdt.w + dtbl);
        Cl[w][r][l] = Cl[w][r][l] * (dt * bc + dsml) * Zl[w][r][l];
    }
    __syncthreads();

    // out-proj + channel weight + residual
    {
        const float4* wo = (const float4*)(Wo + l * 64);
        float4 wv[16];
#pragma unroll
        for (int i = 0; i < 16; ++i) wv[i] = wo[i];
        for (int r = 0; r < 8; ++r) {
            const float4* yr = (const float4*)(&Cl[w][r][0]);
            float a0 = 0.f, a1 = 0.f;
#pragma unroll
            for (int i = 0; i < 16; i += 2) {
                a0 += dot4f(yr[i], wv[i]);
                a1 += dot4f(yr[i + 1], wv[i + 1]);
            }
            s1[((b0 + r) * 12 + c) * 64 + l] = cwc * (a0 + a1) + Xl[w][r][l];
        }
    }
}

// ---------------------------------------------------------------------------
// K2: transformer over C. One wave per b (4 waves/block). lane = token s.
// In-place on io (= d_out). Two-pass softmax, no score array.
// ---------------------------------------------------------------------------
__global__ __launch_bounds__(256, 4) void k2_enc1(
    float* __restrict__ io,           // (8192,12,64) all_out -> x2, in place
    const float* __restrict__ in_w1,  // (36,12)
    const float* __restrict__ in_b1,  // (36)
    const float* __restrict__ ow1,    // (12,12)
    const float* __restrict__ ob1,    // (12)
    const float* __restrict__ n1g, const float* __restrict__ n1b,   // (12)
    const float* __restrict__ m1w1, const float* __restrict__ m1b1, // (24,12),(24)
    const float* __restrict__ m1w2, const float* __restrict__ m1b2) // (12,24),(12)
{
    __shared__ float KV[4][64][25];  // [wave][t][ k0..11 | v0..11 ], pad 25

    const int w = threadIdx.x >> 6;
    const int l = threadIdx.x & 63;
    const int b = blockIdx.x * 4 + w;

    float* io_b = io + b * (12 * 64);

    float tr[12];
#pragma unroll
    for (int i = 0; i < 12; ++i) tr[i] = io_b[i * 64 + l];

    float qreg[12];
#pragma unroll
    for (int e = 0; e < 12; ++e) {
        float acc = in_b1[e];
#pragma unroll
        for (int cc = 0; cc < 12; ++cc) acc += tr[cc] * in_w1[e * 12 + cc];
        qreg[e] = acc * 0.57735026918962576451f;  // 1/sqrt(hd=3)
    }
    for (int e = 12; e < 36; ++e) {  // rolled: no register-array indexing
        float acc = in_b1[e];
#pragma unroll
        for (int cc = 0; cc < 12; ++cc) acc += tr[cc] * in_w1[e * 12 + cc];
        KV[w][l][e - 12] = acc;
    }
    __syncthreads();

    // attention, two-pass softmax per head (scores recomputed, never stored)
    float orow[12];
#pragma unroll
    for (int h = 0; h < 4; ++h) {
        const float q0 = qreg[3 * h + 0], q1 = qreg[3 * h + 1], q2 = qreg[3 * h + 2];
        float mx = -1e30f;
        for (int t = 0; t < 64; ++t) {
            float s = q0 * KV[w][t][3 * h + 0] + q1 * KV[w][t][3 * h + 1] +
                      q2 * KV[w][t][3 * h + 2];
            mx = fmaxf(mx, s);
        }
        float sum = 0.f, o0 = 0.f, o1 = 0.f, o2 = 0.f;
        for (int t = 0; t < 64; ++t) {
            float s = q0 * KV[w][t][3 * h + 0] + q1 * KV[w][t][3 * h + 1] +
                      q2 * KV[w][t][3 * h + 2];
            float p = __expf(s - mx);
            sum += p;
            o0 += p * KV[w][t][12 + 3 * h + 0];
            o1 += p * KV[w][t][12 + 3 * h + 1];
            o2 += p * KV[w][t][12 + 3 * h + 2];
        }
        const float inv = 1.f / sum;
        orow[3 * h + 0] = o0 * inv;
        orow[3 * h + 1] = o1 * inv;
        orow[3 * h + 2] = o2 * inv;
    }

    // out-proj + residual + LN(12)
    float a[12];
#pragma unroll
    for (int cc = 0; cc < 12; ++cc) {
        float acc = ob1[cc];
#pragma unroll
        for (int e = 0; e < 12; ++e) acc += orow[e] * ow1[cc * 12 + e];
        a[cc] = tr[cc] + acc;
    }
    {
        float mu = 0.f;
#pragma unroll
        for (int i = 0; i < 12; ++i) mu += a[i];
        mu *= (1.f / 12.f);
        float var = 0.f;
#pragma unroll
        for (int i = 0; i < 12; ++i) { float d = a[i] - mu; var += d * d; }
        var *= (1.f / 12.f);
        const float rs = rsqrtf(var + 1e-5f);
#pragma unroll
        for (int i = 0; i < 12; ++i) a[i] = (a[i] - mu) * rs * n1g[i] + n1b[i];
    }

    // MLP 12 -> 24 -> 12 (exact gelu), residual; k rolled (no reg-array by k)
    float a2[12];
#pragma unroll
    for (int i = 0; i < 12; ++i) a2[i] = a[i] + m1b2[i];
    for (int k = 0; k < 24; ++k) {
        float acc = m1b1[k];
#pragma unroll
        for (int cc = 0; cc < 12; ++cc) acc += a[cc] * m1w1[k * 12 + cc];
        const float hk = gelu_f(acc);
#pragma unroll
        for (int cc = 0; cc < 12; ++cc) a2[cc] += hk * m1w2[cc * 24 + k];
    }

    // second LN(12) with norm1 params -> x2, in place
    {
        float mu = 0.f;
#pragma unroll
        for (int i = 0; i < 12; ++i) mu += a2[i];
        mu *= (1.f / 12.f);
        float var = 0.f;
#pragma unroll
        for (int i = 0; i < 12; ++i) { float d = a2[i] - mu; var += d * d; }
        var *= (1.f / 12.f);
        const float rs = rsqrtf(var + 1e-5f);
#pragma unroll
        for (int cc = 0; cc < 12; ++cc)
            io_b[cc * 64 + l] = (a2[cc] - mu) * rs * n1g[cc] + n1b[cc];
    }
}

// ---------------------------------------------------------------------------
// K3: transformer over D. One wave per b. S=12, E=64, 8 heads, hd=8.
// QKVH buffer stride 196 (16B-aligned rows). O overlays Q cols 0..63 after
// q-preload (wave-lockstep safe); H overlays K/V cols 64..191 after attn.
// ---------------------------------------------------------------------------
__global__ __launch_bounds__(256, 3) void k3_enc2(
    float* __restrict__ io,           // (8192,12,64) x2 -> out, in place
    const float* __restrict__ in_w2,  // (192,64)
    const float* __restrict__ in_b2,  // (192)
    const float* __restrict__ ow2,    // (64,64)
    const float* __restrict__ ob2,    // (64)
    const float* __restrict__ n2g, const float* __restrict__ n2b,   // (64)
    const float* __restrict__ m2w1, const float* __restrict__ m2b1, // (128,64),(128)
    const float* __restrict__ m2w2, const float* __restrict__ m2b2) // (64,128),(64)
{
    __shared__ __align__(16) float Xs[4][12][68];   // 13056 B
    __shared__ __align__(16) float QH[4][12][196];  // 37632 B; total 50688 B

    const int w = threadIdx.x >> 6;
    const int l = threadIdx.x & 63;
    const int b = blockIdx.x * 4 + w;

    float* io_b = io + b * (12 * 64);
#pragma unroll
    for (int t = 0; t < 12; ++t) Xs[w][t][l] = io_b[t * 64 + l];
    __syncthreads();

    // qkv: lane owns cols e = k*64 + l; weight row hoisted per k
    for (int k = 0; k < 3; ++k) {
        const int e = k * 64 + l;
        const float4* Wrow = (const float4*)(in_w2 + e * 64);
        float4 wv[16];
#pragma unroll
        for (int i = 0; i < 16; ++i) wv[i] = Wrow[i];
        const float bias = in_b2[e];
        const float scale = (k == 0) ? 0.35355339059327376220f : 1.f;  // hd=8
#pragma unroll
        for (int t = 0; t < 12; ++t) {
            const float4* xrow = (const float4*)(&Xs[w][t][0]);
            float a0 = 0.f, a1 = 0.f;
#pragma unroll
            for (int i = 0; i < 16; i += 2) {
                a0 += dot4f(xrow[i], wv[i]);
                a1 += dot4f(xrow[i + 1], wv[i + 1]);
            }
            QH[w][t][e] = ((a0 + a1) + bias) * scale;
        }
    }
    __syncthreads();

    // attention: 96 (h,s) tasks over 64 lanes x 2 reps. Preload ALL q before
    // any O write (O overlays Q cols 0..63; wave-lockstep makes this safe).
    {
        const int h0 = l / 12, s0 = l - h0 * 12;          // rep0: always valid
        const int r1 = l + 64;
        const int h1 = r1 / 12, s1 = r1 - h1 * 12;        // rep1: valid iff r1<96
        const bool v1 = (r1 < 96);
        float q0v[8], q1v[8];
#pragma unroll
        for (int d = 0; d < 8; ++d) q0v[d] = QH[w][s0][h0 * 8 + d];
#pragma unroll
        for (int d = 0; d < 8; ++d) q1v[d] = QH[w][s1][h1 * 8 + d];  // in-bounds garbage ok

        // rep 0
        {
            float scv[12], mx = -1e30f;
#pragma unroll
            for (int t = 0; t < 12; ++t) {
                float acc = 0.f;
#pragma unroll
                for (int d = 0; d < 8; ++d) acc += q0v[d] * QH[w][t][64 + h0 * 8 + d];
                scv[t] = acc;
                mx = fmaxf(mx, acc);
            }
            float sum = 0.f;
#pragma unroll
            for (int t = 0; t < 12; ++t) { float p = __expf(scv[t] - mx); scv[t] = p; sum += p; }
            const float inv = 1.f / sum;
#pragma unroll
            for (int d = 0; d < 8; ++d) {
                float o = 0.f;
#pragma unroll
                for (int t = 0; t < 12; ++t) o += scv[t] * QH[w][t][128 + h0 * 8 + d];
                QH[w][s0][h0 * 8 + d] = o * inv;   // O overlays Q
            }
        }
        // rep 1
        if (v1) {
            float scv[12], mx = -1e30f;
#pragma unroll
            for (int t = 0; t < 12; ++t) {
                float acc = 0.f;
#pragma unroll
                for (int d = 0; d < 8; ++d) acc += q1v[d] * QH[w][t][64 + h1 * 8 + d];
                scv[t] = acc;
                mx = fmaxf(mx, acc);
            }
            float sum = 0.f;
#pragma unroll
            for (int t = 0; t < 12; ++t) { float p = __expf(scv[t] - mx); scv[t] = p; sum += p; }
            const float inv = 1.f / sum;
#pragma unroll
            for (int d = 0; d < 8; ++d) {
                float o = 0.f;
#pragma unroll
                for (int t = 0; t < 12; ++t) o += scv[t] * QH[w][t][128 + h1 * 8 + d];
                QH[w][s1][h1 * 8 + d] = o * inv;
            }
        }
    }
    __syncthreads();

    // out-proj + residual + LN(64, cross-lane). O rows at QH[w][t][0..63].
    float xa[12];
    {
        const float4* Wrow = (const float4*)(ow2 + l * 64);
        float4 wv[16];
#pragma unroll
        for (int i = 0; i < 16; ++i) wv[i] = Wrow[i];
        const float bias = ob2[l];
        const float gg = n2g[l], bb = n2b[l];
#pragma unroll
        for (int t = 0; t < 12; ++t) {
            const float4* orow = (const float4*)(&QH[w][t][0]);
            float a0 = 0.f, a1 = 0.f;
#pragma unroll
            for (int i = 0; i < 16; i += 2) {
                a0 += dot4f(orow[i], wv[i]);
                a1 += dot4f(orow[i + 1], wv[i + 1]);
            }
            float v = Xs[w][t][l] + (a0 + a1) + bias;
            const float mu = wave_sum64(v) * (1.f / 64.f);
            const float dv = v - mu;
            const float var = wave_sum64(dv * dv) * (1.f / 64.f);
            const float vn = dv * rsqrtf(var + 1e-5f) * gg + bb;
            xa[t] = vn;
            Xs[w][t][l] = vn;
        }
    }
    __syncthreads();

    // MLP hidden 64 -> 128 (exact gelu); H overlays K/V: QH[w][t][64+kk]
    for (int k = 0; k < 2; ++k) {
        const int kk = k * 64 + l;
        const float4* Wrow = (const float4*)(m2w1 + kk * 64);
        float4 wv[16];
#pragma unroll
        for (int i = 0; i < 16; ++i) wv[i] = Wrow[i];
        const float bias = m2b1[kk];
#pragma unroll
        for (int t = 0; t < 12; ++t) {
            const float4* xrow = (const float4*)(&Xs[w][t][0]);
            float a0 = 0.f, a1 = 0.f;
#pragma unroll
            for (int i = 0; i < 16; i += 2) {
                a0 += dot4f(xrow[i], wv[i]);
                a1 += dot4f(xrow[i + 1], wv[i + 1]);
            }
            QH[w][t][64 + kk] = gelu_f((a0 + a1) + bias);
        }
    }
    __syncthreads();

    // MLP out 128 -> 64 + residual + final LN(64), write output in place
    float accf[12];
#pragma unroll
    for (int t = 0; t < 12; ++t) accf[t] = m2b2[l];
    for (int k = 0; k < 2; ++k) {
        const float4* Wrow = (const float4*)(m2w2 + l * 128 + k * 64);
        float4 wv[16];
#pragma unroll
        for (int i = 0; i < 16; ++i) wv[i] = Wrow[i];
#pragma unroll
        for (int t = 0; t < 12; ++t) {
            const float4* hrow = (const float4*)(&QH[w][t][64 + k * 64]);
            float a0 = 0.f, a1 = 0.f;
#pragma unroll
            for (int i = 0; i < 16; i += 2) {
                a0 += dot4f(hrow[i], wv[i]);
                a1 += dot4f(hrow[i + 1], wv[i + 1]);
            }
            accf[t] += (a0 + a1);
        }
    }
    {
        const float gg = n2g[l], bb = n2b[l];
#pragma unroll
        for (int t = 0; t < 12; ++t) {
            float v = xa[t] + accf[t];
            const float mu = wave_sum64(v) * (1.f / 64.f);
            const float dv = v - mu;
            const float var = wave_sum64(dv * dv) * (1.f / 64.f);
            io_b[t * 64 + l] = dv * rsqrtf(var + 1e-5f) * gg + bb;
        }
    }
}

// ---------------------------------------------------------------------------
extern "C" void kernel_launch(void* const* d_in, const int* in_sizes, int n_in,
                              void* d_out, int out_size, void* d_ws, size_t ws_size,
                              hipStream_t stream) {
    (void)in_sizes; (void)n_in; (void)d_ws; (void)ws_size; (void)out_size;

    const float* x          = (const float*)d_in[0];
    const float* in_proj_w  = (const float*)d_in[2];
    const float* conv_w     = (const float*)d_in[3];
    const float* conv_b     = (const float*)d_in[4];
    const float* x_proj_w   = (const float*)d_in[5];
    const float* dt_proj_w  = (const float*)d_in[6];
    const float* dt_proj_b  = (const float*)d_in[7];
    const float* D_ssm      = (const float*)d_in[9];
    const float* out_proj_w = (const float*)d_in[10];
    const float* channel_w  = (const float*)d_in[11];
    const float* a1_in_w  = (const float*)d_in[12];
    const float* a1_in_b  = (const float*)d_in[13];
    const float* a1_out_w = (const float*)d_in[14];
    const float* a1_out_b = (const float*)d_in[15];
    const float* a2_in_w  = (const float*)d_in[16];
    const float* a2_in_b  = (const float*)d_in[17];
    const float* a2_out_w = (const float*)d_in[18];
    const float* a2_out_b = (const float*)d_in[19];
    const float* n1g = (const float*)d_in[20];
    const float* n1b = (const float*)d_in[21];
    const float* n2g = (const float*)d_in[22];
    const float* n2b = (const float*)d_in[23];
    const float* m1w1 = (const float*)d_in[24];
    const float* m1b1 = (const float*)d_in[25];
    const float* m1w2 = (const float*)d_in[26];
    const float* m1b2 = (const float*)d_in[27];
    const float* m2w1 = (const float*)d_in[28];
    const float* m2b1 = (const float*)d_in[29];
    const float* m2w2 = (const float*)d_in[30];
    const float* m2b2 = (const float*)d_in[31];

    float* io = (float*)d_out;  // K1 writes all_out; K2, K3 run in place

    k1_mamba<<<dim3(8192 / 32, 12), 256, 0, stream>>>(
        x, in_proj_w, conv_w, conv_b, x_proj_w, dt_proj_w, dt_proj_b,
        D_ssm, out_proj_w, channel_w, io);

    k2_enc1<<<dim3(8192 / 4), 256, 0, stream>>>(
        io, a1_in_w, a1_in_b, a1_out_w, a1_out_b,
        n1g, n1b, m1w1, m1b1, m1w2, m1b2);

    k3_enc2<<<dim3(8192 / 4), 256, 0, stream>>>(
        io, a2_in_w, a2_in_b, a2_out_w, a2_out_b,
        n2g, n2b, m2w1, m2b1, m2w2, m2b2);
}

// Round 6
// 1364.089 us; speedup vs baseline: 2.3687x; 1.9676x over previous
//
#include <hip/hip_runtime.h>
#include <math.h>

// ---------------------------------------------------------------------------
// EncoderLayer: B=8192, C=12, D=64.
// K1: mamba block. lane = e; one wave = 8 b-rows of one c. -> all_out (d_out)
// K2: transformer over C (4 heads, S=64, E=12). In-place on d_out.
// K3: transformer over D (8 heads, S=12, E=64). In-place on d_out.
// All f32. Dead paths (x123/dense, A_log, conv_w[...,0]) skipped.
//
// SPILL DISCIPLINE (r4 post-mortem): launch_bounds second arg produced an
// 84-VGPR cap (6 waves/EU granule) and every float4 wv[16] hoist (64 regs)
// spilled -> 4.8 GB scratch traffic/dispatch. Now: plain launch_bounds(256),
// all weight-row hoists are wv[8] (32 regs) in two half-row passes over a
// persistent acc[] -> peak live ~60 VGPR, spill impossible.
// (r5 was an infra flake — "container failed twice", no pytest output —
//  resubmitting unchanged to measure the spill fix.)
// ---------------------------------------------------------------------------

__device__ __forceinline__ float dot4f(const float4 a, const float4 b) {
    return a.x * b.x + a.y * b.y + a.z * b.z + a.w * b.w;
}
__device__ __forceinline__ float silu_f(float x) { return x / (1.f + __expf(-x)); }
__device__ __forceinline__ float softplus_f(float x) {
    return fmaxf(x, 0.f) + log1pf(__expf(-fabsf(x)));
}
__device__ __forceinline__ float gelu_f(float x) {
    return 0.5f * x * (1.f + erff(x * 0.70710678118654752440f));
}
__device__ __forceinline__ float wave_sum64(float v) {
#pragma unroll
    for (int m = 32; m > 0; m >>= 1) v += __shfl_xor(v, m, 64);
    return v;
}

// ---------------------------------------------------------------------------
// K1: mamba. grid (256, 12), block 256 = 4 waves. Wave w: c = blockIdx.y,
// b-range [(blockIdx.x*4+w)*8, +8). lane = channel e.
// ---------------------------------------------------------------------------
__global__ __launch_bounds__(256) void k1_mamba(
    const float* __restrict__ x,          // (8192,12,64)
    const float* __restrict__ in_proj_w,  // (12,128,64)
    const float* __restrict__ conv_w,     // (12,64,2)
    const float* __restrict__ conv_b,     // (12,64)
    const float* __restrict__ x_proj_w,   // (12,16,64)
    const float* __restrict__ dt_proj_w,  // (12,64,4)
    const float* __restrict__ dt_proj_b,  // (12,64)
    const float* __restrict__ D_ssm,      // (12,64)
    const float* __restrict__ out_proj_w, // (12,64,64)
    const float* __restrict__ channel_w,  // (12)
    float* __restrict__ s1)               // (8192,12,64) all_out
{
    __shared__ __align__(16) float Xl[4][8][68];  // x rows (residual)
    __shared__ __align__(16) float Cl[4][8][68];  // xc, then y
    __shared__ __align__(16) float Zl[4][8][68];  // silu(z)
    __shared__ __align__(16) float Pr[4][8][16];  // proj

    const int w  = threadIdx.x >> 6;
    const int l  = threadIdx.x & 63;
    const int c  = blockIdx.y;
    const int b0 = (blockIdx.x * 4 + w) * 8;

    const float cw1  = conv_w[c * 128 + 2 * l + 1];
    const float cbl  = conv_b[c * 64 + l];
    const float4 wdt = *(const float4*)(dt_proj_w + c * 256 + 4 * l);
    const float dtbl = dt_proj_b[c * 64 + l];
    const float dsml = D_ssm[c * 64 + l];
    const float cwc  = channel_w[c];

    const float* Wi = in_proj_w + c * (128 * 64);
    const float* Wp = x_proj_w + c * (16 * 64);
    const float* Wo = out_proj_w + c * (64 * 64);

    for (int r = 0; r < 8; ++r)
        Xl[w][r][l] = x[((b0 + r) * 12 + c) * 64 + l];
    __syncthreads();

    // pass A1: xs dot (row l of Wi) -> xc.  acc[8] + wv[8] halves.
    {
        const float4* WiA = (const float4*)(Wi + l * 64);
        float acc[8];
#pragma unroll
        for (int r = 0; r < 8; ++r) acc[r] = 0.f;
#pragma unroll
        for (int half = 0; half < 2; ++half) {
            float4 wv[8];
#pragma unroll
            for (int i = 0; i < 8; ++i) wv[i] = WiA[half * 8 + i];
#pragma unroll
            for (int r = 0; r < 8; ++r) {
                const float4* xr = (const float4*)(&Xl[w][r][0]) + half * 8;
                float a0 = 0.f, a1 = 0.f;
#pragma unroll
                for (int i = 0; i < 8; i += 2) {
                    a0 += dot4f(xr[i], wv[i]);
                    a1 += dot4f(xr[i + 1], wv[i + 1]);
                }
                acc[r] += a0 + a1;
            }
        }
#pragma unroll
        for (int r = 0; r < 8; ++r)
            Cl[w][r][l] = silu_f(acc[r] * cw1 + cbl);
    }
    // pass A2: z dot (row 64+l of Wi) -> silu(z)
    {
        const float4* WiB = (const float4*)(Wi + (64 + l) * 64);
        float acc[8];
#pragma unroll
        for (int r = 0; r < 8; ++r) acc[r] = 0.f;
#pragma unroll
        for (int half = 0; half < 2; ++half) {
            float4 wv[8];
#pragma unroll
            for (int i = 0; i < 8; ++i) wv[i] = WiB[half * 8 + i];
#pragma unroll
            for (int r = 0; r < 8; ++r) {
                const float4* xr = (const float4*)(&Xl[w][r][0]) + half * 8;
                float a0 = 0.f, a1 = 0.f;
#pragma unroll
                for (int i = 0; i < 8; i += 2) {
                    a0 += dot4f(xr[i], wv[i]);
                    a1 += dot4f(xr[i + 1], wv[i + 1]);
                }
                acc[r] += a0 + a1;
            }
        }
#pragma unroll
        for (int r = 0; r < 8; ++r)
            Zl[w][r][l] = silu_f(acc[r]);
    }
    __syncthreads();

    // proj: 128 (r,f) tasks over 64 lanes (2 per lane), wv[8] halves
    {
        const int f = l & 15;
        const float4* wp = (const float4*)(Wp + f * 64);
        float acc[2];
        acc[0] = 0.f; acc[1] = 0.f;
#pragma unroll
        for (int half = 0; half < 2; ++half) {
            float4 wv[8];
#pragma unroll
            for (int i = 0; i < 8; ++i) wv[i] = wp[half * 8 + i];
#pragma unroll
            for (int task = 0; task < 2; ++task) {
                const int r = (l >> 4) + 4 * task;
                const float4* xc4 = (const float4*)(&Cl[w][r][0]) + half * 8;
                float a0 = 0.f, a1 = 0.f;
#pragma unroll
                for (int i = 0; i < 8; i += 2) {
                    a0 += dot4f(xc4[i], wv[i]);
                    a1 += dot4f(xc4[i + 1], wv[i + 1]);
                }
                acc[task] += a0 + a1;
            }
        }
        Pr[w][(l >> 4) + 0][f] = acc[0];
        Pr[w][(l >> 4) + 4][f] = acc[1];
    }
    __syncthreads();

    // y = xc * (dt*bc + D) * silu(z)   (overwrites Cl)
    for (int r = 0; r < 8; ++r) {
        const float* pr = &Pr[w][r][0];
        const float bc = pr[4] * pr[10] + pr[5] * pr[11] + pr[6] * pr[12] +
                         pr[7] * pr[13] + pr[8] * pr[14] + pr[9] * pr[15];
        const float dt = softplus_f(pr[0] * wdt.x + pr[1] * wdt.y +
                                    pr[2] * wdt.z + pr[3] * wdt.w + dtbl);
        Cl[w][r][l] = Cl[w][r][l] * (dt * bc + dsml) * Zl[w][r][l];
    }
    __syncthreads();

    // out-proj + channel weight + residual
    {
        const float4* wo = (const float4*)(Wo + l * 64);
        float acc[8];
#pragma unroll
        for (int r = 0; r < 8; ++r) acc[r] = 0.f;
#pragma unroll
        for (int half = 0; half < 2; ++half) {
            float4 wv[8];
#pragma unroll
            for (int i = 0; i < 8; ++i) wv[i] = wo[half * 8 + i];
#pragma unroll
            for (int r = 0; r < 8; ++r) {
                const float4* yr = (const float4*)(&Cl[w][r][0]) + half * 8;
                float a0 = 0.f, a1 = 0.f;
#pragma unroll
                for (int i = 0; i < 8; i += 2) {
                    a0 += dot4f(yr[i], wv[i]);
                    a1 += dot4f(yr[i + 1], wv[i + 1]);
                }
                acc[r] += a0 + a1;
            }
        }
#pragma unroll
        for (int r = 0; r < 8; ++r)
            s1[((b0 + r) * 12 + c) * 64 + l] = cwc * acc[r] + Xl[w][r][l];
    }
}

// ---------------------------------------------------------------------------
// K2: transformer over C. One wave per b (4 waves/block). lane = token s.
// In-place on io (= d_out). Two-pass softmax, no score array.
// ---------------------------------------------------------------------------
__global__ __launch_bounds__(256) void k2_enc1(
    float* __restrict__ io,           // (8192,12,64) all_out -> x2, in place
    const float* __restrict__ in_w1,  // (36,12)
    const float* __restrict__ in_b1,  // (36)
    const float* __restrict__ ow1,    // (12,12)
    const float* __restrict__ ob1,    // (12)
    const float* __restrict__ n1g, const float* __restrict__ n1b,   // (12)
    const float* __restrict__ m1w1, const float* __restrict__ m1b1, // (24,12),(24)
    const float* __restrict__ m1w2, const float* __restrict__ m1b2) // (12,24),(12)
{
    __shared__ float KV[4][64][25];  // [wave][t][ k0..11 | v0..11 ], pad 25

    const int w = threadIdx.x >> 6;
    const int l = threadIdx.x & 63;
    const int b = blockIdx.x * 4 + w;

    float* io_b = io + b * (12 * 64);

    float tr[12];
#pragma unroll
    for (int i = 0; i < 12; ++i) tr[i] = io_b[i * 64 + l];

    float qreg[12];
#pragma unroll
    for (int e = 0; e < 12; ++e) {
        float acc = in_b1[e];
#pragma unroll
        for (int cc = 0; cc < 12; ++cc) acc += tr[cc] * in_w1[e * 12 + cc];
        qreg[e] = acc * 0.57735026918962576451f;  // 1/sqrt(hd=3)
    }
    for (int e = 12; e < 36; ++e) {  // rolled: no register-array indexing
        float acc = in_b1[e];
#pragma unroll
        for (int cc = 0; cc < 12; ++cc) acc += tr[cc] * in_w1[e * 12 + cc];
        KV[w][l][e - 12] = acc;
    }
    __syncthreads();

    // attention, two-pass softmax per head (scores recomputed, never stored)
    float orow[12];
#pragma unroll
    for (int h = 0; h < 4; ++h) {
        const float q0 = qreg[3 * h + 0], q1 = qreg[3 * h + 1], q2 = qreg[3 * h + 2];
        float mx = -1e30f;
        for (int t = 0; t < 64; ++t) {
            float s = q0 * KV[w][t][3 * h + 0] + q1 * KV[w][t][3 * h + 1] +
                      q2 * KV[w][t][3 * h + 2];
            mx = fmaxf(mx, s);
        }
        float sum = 0.f, o0 = 0.f, o1 = 0.f, o2 = 0.f;
        for (int t = 0; t < 64; ++t) {
            float s = q0 * KV[w][t][3 * h + 0] + q1 * KV[w][t][3 * h + 1] +
                      q2 * KV[w][t][3 * h + 2];
            float p = __expf(s - mx);
            sum += p;
            o0 += p * KV[w][t][12 + 3 * h + 0];
            o1 += p * KV[w][t][12 + 3 * h + 1];
            o2 += p * KV[w][t][12 + 3 * h + 2];
        }
        const float inv = 1.f / sum;
        orow[3 * h + 0] = o0 * inv;
        orow[3 * h + 1] = o1 * inv;
        orow[3 * h + 2] = o2 * inv;
    }

    // out-proj + residual + LN(12)
    float a[12];
#pragma unroll
    for (int cc = 0; cc < 12; ++cc) {
        float acc = ob1[cc];
#pragma unroll
        for (int e = 0; e < 12; ++e) acc += orow[e] * ow1[cc * 12 + e];
        a[cc] = tr[cc] + acc;
    }
    {
        float mu = 0.f;
#pragma unroll
        for (int i = 0; i < 12; ++i) mu += a[i];
        mu *= (1.f / 12.f);
        float var = 0.f;
#pragma unroll
        for (int i = 0; i < 12; ++i) { float d = a[i] - mu; var += d * d; }
        var *= (1.f / 12.f);
        const float rs = rsqrtf(var + 1e-5f);
#pragma unroll
        for (int i = 0; i < 12; ++i) a[i] = (a[i] - mu) * rs * n1g[i] + n1b[i];
    }

    // MLP 12 -> 24 -> 12 (exact gelu), residual; k rolled (no reg-array by k)
    float a2[12];
#pragma unroll
    for (int i = 0; i < 12; ++i) a2[i] = a[i] + m1b2[i];
    for (int k = 0; k < 24; ++k) {
        float acc = m1b1[k];
#pragma unroll
        for (int cc = 0; cc < 12; ++cc) acc += a[cc] * m1w1[k * 12 + cc];
        const float hk = gelu_f(acc);
#pragma unroll
        for (int cc = 0; cc < 12; ++cc) a2[cc] += hk * m1w2[cc * 24 + k];
    }

    // second LN(12) with norm1 params -> x2, in place
    {
        float mu = 0.f;
#pragma unroll
        for (int i = 0; i < 12; ++i) mu += a2[i];
        mu *= (1.f / 12.f);
        float var = 0.f;
#pragma unroll
        for (int i = 0; i < 12; ++i) { float d = a2[i] - mu; var += d * d; }
        var *= (1.f / 12.f);
        const float rs = rsqrtf(var + 1e-5f);
#pragma unroll
        for (int cc = 0; cc < 12; ++cc)
            io_b[cc * 64 + l] = (a2[cc] - mu) * rs * n1g[cc] + n1b[cc];
    }
}

// ---------------------------------------------------------------------------
// K3: transformer over D. One wave per b. S=12, E=64, 8 heads, hd=8.
// QKVH buffer stride 196 (16B-aligned rows). O overlays Q cols 0..63 after
// q-preload; H overlays K/V cols 64..191 after attention.
// All matmul phases: acc[12] + wv[8] half-row passes (low VGPR, no spill).
// ---------------------------------------------------------------------------
__global__ __launch_bounds__(256) void k3_enc2(
    float* __restrict__ io,           // (8192,12,64) x2 -> out, in place
    const float* __restrict__ in_w2,  // (192,64)
    const float* __restrict__ in_b2,  // (192)
    const float* __restrict__ ow2,    // (64,64)
    const float* __restrict__ ob2,    // (64)
    const float* __restrict__ n2g, const float* __restrict__ n2b,   // (64)
    const float* __restrict__ m2w1, const float* __restrict__ m2b1, // (128,64),(128)
    const float* __restrict__ m2w2, const float* __restrict__ m2b2) // (64,128),(64)
{
    __shared__ __align__(16) float Xs[4][12][68];   // 13056 B
    __shared__ __align__(16) float QH[4][12][196];  // 37632 B; total 50688 B

    const int w = threadIdx.x >> 6;
    const int l = threadIdx.x & 63;
    const int b = blockIdx.x * 4 + w;

    float* io_b = io + b * (12 * 64);
#pragma unroll
    for (int t = 0; t < 12; ++t) Xs[w][t][l] = io_b[t * 64 + l];
    __syncthreads();

    // qkv: lane owns cols e = k*64 + l; half-row weight passes
    for (int k = 0; k < 3; ++k) {
        const int e = k * 64 + l;
        const float4* Wrow = (const float4*)(in_w2 + e * 64);
        const float bias = in_b2[e];
        const float scale = (k == 0) ? 0.35355339059327376220f : 1.f;  // hd=8
        float acc[12];
#pragma unroll
        for (int t = 0; t < 12; ++t) acc[t] = 0.f;
#pragma unroll
        for (int half = 0; half < 2; ++half) {
            float4 wv[8];
#pragma unroll
            for (int i = 0; i < 8; ++i) wv[i] = Wrow[half * 8 + i];
#pragma unroll
            for (int t = 0; t < 12; ++t) {
                const float4* xrow = (const float4*)(&Xs[w][t][0]) + half * 8;
                float a0 = 0.f, a1 = 0.f;
#pragma unroll
                for (int i = 0; i < 8; i += 2) {
                    a0 += dot4f(xrow[i], wv[i]);
                    a1 += dot4f(xrow[i + 1], wv[i + 1]);
                }
                acc[t] += a0 + a1;
            }
        }
#pragma unroll
        for (int t = 0; t < 12; ++t)
            QH[w][t][e] = (acc[t] + bias) * scale;
    }
    __syncthreads();

    // attention: 96 (h,s) tasks over 64 lanes x 2 reps. Preload ALL q before
    // any O write (O overlays Q cols 0..63; wave-lockstep makes this safe).
    {
        const int h0 = l / 12, s0 = l - h0 * 12;          // rep0: always valid
        const int r1 = l + 64;
        const int h1 = r1 / 12, s1 = r1 - h1 * 12;        // rep1: valid iff r1<96
        const bool v1 = (r1 < 96);
        float q0v[8], q1v[8];
#pragma unroll
        for (int d = 0; d < 8; ++d) q0v[d] = QH[w][s0][h0 * 8 + d];
#pragma unroll
        for (int d = 0; d < 8; ++d) q1v[d] = QH[w][s1][h1 * 8 + d];  // in-bounds garbage ok

        // rep 0
        {
            float scv[12], mx = -1e30f;
#pragma unroll
            for (int t = 0; t < 12; ++t) {
                float acc = 0.f;
#pragma unroll
                for (int d = 0; d < 8; ++d) acc += q0v[d] * QH[w][t][64 + h0 * 8 + d];
                scv[t] = acc;
                mx = fmaxf(mx, acc);
            }
            float sum = 0.f;
#pragma unroll
            for (int t = 0; t < 12; ++t) { float p = __expf(scv[t] - mx); scv[t] = p; sum += p; }
            const float inv = 1.f / sum;
#pragma unroll
            for (int d = 0; d < 8; ++d) {
                float o = 0.f;
#pragma unroll
                for (int t = 0; t < 12; ++t) o += scv[t] * QH[w][t][128 + h0 * 8 + d];
                QH[w][s0][h0 * 8 + d] = o * inv;   // O overlays Q
            }
        }
        // rep 1
        if (v1) {
            float scv[12], mx = -1e30f;
#pragma unroll
            for (int t = 0; t < 12; ++t) {
                float acc = 0.f;
#pragma unroll
                for (int d = 0; d < 8; ++d) acc += q1v[d] * QH[w][t][64 + h1 * 8 + d];
                scv[t] = acc;
                mx = fmaxf(mx, acc);
            }
            float sum = 0.f;
#pragma unroll
            for (int t = 0; t < 12; ++t) { float p = __expf(scv[t] - mx); scv[t] = p; sum += p; }
            const float inv = 1.f / sum;
#pragma unroll
            for (int d = 0; d < 8; ++d) {
                float o = 0.f;
#pragma unroll
                for (int t = 0; t < 12; ++t) o += scv[t] * QH[w][t][128 + h1 * 8 + d];
                QH[w][s1][h1 * 8 + d] = o * inv;
            }
        }
    }
    __syncthreads();

    // out-proj + residual + LN(64, cross-lane). O rows at QH[w][t][0..63].
    float xa[12];
    {
        const float4* Wrow = (const float4*)(ow2 + l * 64);
        const float bias = ob2[l];
        float acc[12];
#pragma unroll
        for (int t = 0; t < 12; ++t) acc[t] = 0.f;
#pragma unroll
        for (int half = 0; half < 2; ++half) {
            float4 wv[8];
#pragma unroll
            for (int i = 0; i < 8; ++i) wv[i] = Wrow[half * 8 + i];
#pragma unroll
            for (int t = 0; t < 12; ++t) {
                const float4* orow = (const float4*)(&QH[w][t][0]) + half * 8;
                float a0 = 0.f, a1 = 0.f;
#pragma unroll
                for (int i = 0; i < 8; i += 2) {
                    a0 += dot4f(orow[i], wv[i]);
                    a1 += dot4f(orow[i + 1], wv[i + 1]);
                }
                acc[t] += a0 + a1;
            }
        }
        const float gg = n2g[l], bb = n2b[l];
#pragma unroll
        for (int t = 0; t < 12; ++t) {
            float v = Xs[w][t][l] + acc[t] + bias;
            const float mu = wave_sum64(v) * (1.f / 64.f);
            const float dv = v - mu;
            const float var = wave_sum64(dv * dv) * (1.f / 64.f);
            const float vn = dv * rsqrtf(var + 1e-5f) * gg + bb;
            xa[t] = vn;
            Xs[w][t][l] = vn;
        }
    }
    __syncthreads();

    // MLP hidden 64 -> 128 (exact gelu); H overlays K/V: QH[w][t][64+kk]
    for (int k = 0; k < 2; ++k) {
        const int kk = k * 64 + l;
        const float4* Wrow = (const float4*)(m2w1 + kk * 64);
        const float bias = m2b1[kk];
        float acc[12];
#pragma unroll
        for (int t = 0; t < 12; ++t) acc[t] = 0.f;
#pragma unroll
        for (int half = 0; half < 2; ++half) {
            float4 wv[8];
#pragma unroll
            for (int i = 0; i < 8; ++i) wv[i] = Wrow[half * 8 + i];
#pragma unroll
            for (int t = 0; t < 12; ++t) {
                const float4* xrow = (const float4*)(&Xs[w][t][0]) + half * 8;
                float a0 = 0.f, a1 = 0.f;
#pragma unroll
                for (int i = 0; i < 8; i += 2) {
                    a0 += dot4f(xrow[i], wv[i]);
                    a1 += dot4f(xrow[i + 1], wv[i + 1]);
                }
                acc[t] += a0 + a1;
            }
        }
#pragma unroll
        for (int t = 0; t < 12; ++t)
            QH[w][t][64 + kk] = gelu_f(acc[t] + bias);
    }
    __syncthreads();

    // MLP out 128 -> 64 + residual + final LN(64), write output in place
    float accf[12];
#pragma unroll
    for (int t = 0; t < 12; ++t) accf[t] = m2b2[l];
    for (int k = 0; k < 2; ++k) {
        const float4* Wrow = (const float4*)(m2w2 + l * 128 + k * 64);
#pragma unroll
        for (int half = 0; half < 2; ++half) {
            float4 wv[8];
#pragma unroll
            for (int i = 0; i < 8; ++i) wv[i] = Wrow[half * 8 + i];
#pragma unroll
            for (int t = 0; t < 12; ++t) {
                const float4* hrow = (const float4*)(&QH[w][t][64 + k * 64]) + half * 8;
                float a0 = 0.f, a1 = 0.f;
#pragma unroll
                for (int i = 0; i < 8; i += 2) {
                    a0 += dot4f(hrow[i], wv[i]);
                    a1 += dot4f(hrow[i + 1], wv[i + 1]);
                }
                accf[t] += a0 + a1;
            }
        }
    }
    {
        const float gg = n2g[l], bb = n2b[l];
#pragma unroll
        for (int t = 0; t < 12; ++t) {
            float v = xa[t] + accf[t];
            const float mu = wave_sum64(v) * (1.f / 64.f);
            const float dv = v - mu;
            const float var = wave_sum64(dv * dv) * (1.f / 64.f);
            io_b[t * 64 + l] = dv * rsqrtf(var + 1e-5f) * gg + bb;
        }
    }
}

// ---------------------------------------------------------------------------
extern "C" void kernel_launch(void* const* d_in, const int* in_sizes, int n_in,
                              void* d_out, int out_size, void* d_ws, size_t ws_size,
                              hipStream_t stream) {
    (void)in_sizes; (void)n_in; (void)d_ws; (void)ws_size; (void)out_size;

    const float* x          = (const float*)d_in[0];
    const float* in_proj_w  = (const float*)d_in[2];
    const float* conv_w     = (const float*)d_in[3];
    const float* conv_b     = (const float*)d_in[4];
    const float* x_proj_w   = (const float*)d_in[5];
    const float* dt_proj_w  = (const float*)d_in[6];
    const float* dt_proj_b  = (const float*)d_in[7];
    const float* D_ssm      = (const float*)d_in[9];
    const float* out_proj_w = (const float*)d_in[10];
    const float* channel_w  = (const float*)d_in[11];
    const float* a1_in_w  = (const float*)d_in[12];
    const float* a1_in_b  = (const float*)d_in[13];
    const float* a1_out_w = (const float*)d_in[14];
    const float* a1_out_b = (const float*)d_in[15];
    const float* a2_in_w  = (const float*)d_in[16];
    const float* a2_in_b  = (const float*)d_in[17];
    const float* a2_out_w = (const float*)d_in[18];
    const float* a2_out_b = (const float*)d_in[19];
    const float* n1g = (const float*)d_in[20];
    const float* n1b = (const float*)d_in[21];
    const float* n2g = (const float*)d_in[22];
    const float* n2b = (const float*)d_in[23];
    const float* m1w1 = (const float*)d_in[24];
    const float* m1b1 = (const float*)d_in[25];
    const float* m1w2 = (const float*)d_in[26];
    const float* m1b2 = (const float*)d_in[27];
    const float* m2w1 = (const float*)d_in[28];
    const float* m2b1 = (const float*)d_in[29];
    const float* m2w2 = (const float*)d_in[30];
    const float* m2b2 = (const float*)d_in[31];

    float* io = (float*)d_out;  // K1 writes all_out; K2, K3 run in place

    k1_mamba<<<dim3(8192 / 32, 12), 256, 0, stream>>>(
        x, in_proj_w, conv_w, conv_b, x_proj_w, dt_proj_w, dt_proj_b,
        D_ssm, out_proj_w, channel_w, io);

    k2_enc1<<<dim3(8192 / 4), 256, 0, stream>>>(
        io, a1_in_w, a1_in_b, a1_out_w, a1_out_b,
        n1g, n1b, m1w1, m1b1, m1w2, m1b2);

    k3_enc2<<<dim3(8192 / 4), 256, 0, stream>>>(
        io, a2_in_w, a2_in_b, a2_out_w, a2_out_b,
        n2g, n2b, m2w1, m2b1, m2w2, m2b2);
}

// Round 7
// 1276.383 us; speedup vs baseline: 2.5315x; 1.0687x over previous
//
#include <hip/hip_runtime.h>
#include <math.h>

// ---------------------------------------------------------------------------
// EncoderLayer: B=8192, C=12, D=64.
// K1: mamba block. lane = e; one wave = 8 b-rows of one c. -> all_out (d_out)
// K2: transformer over C (4 heads, S=64, E=12). In-place on d_out.
// K3: transformer over D (8 heads, S=12, E=64). In-place on d_out.
// All f32. Dead paths (x123/dense, A_log, conv_w[...,0]) skipped.
//
// SPILL DISCIPLINE (r6 post-mortem): VGPR=256 + symmetric 0.7GB excess
// fetch/write despite ~60-90 live regs per phase => the pre-RA scheduler
// hoists later phases' global weight loads (and unrolls/interleaves the
// trip-3 k-loop) across __syncthreads to hide latency, manufacturing >256
// demand. Fix: PHASE_FENCE (sched_barrier(0) + asm memory clobber) between
// all phases, and unroll(disable)+fence on phase-iteration loops. Weight
// hoists stay wv[8] (32 regs) half-row passes.
// ---------------------------------------------------------------------------

#define PHASE_FENCE() do { __builtin_amdgcn_sched_barrier(0); \
                           asm volatile("" ::: "memory"); } while (0)

__device__ __forceinline__ float dot4f(const float4 a, const float4 b) {
    return a.x * b.x + a.y * b.y + a.z * b.z + a.w * b.w;
}
__device__ __forceinline__ float silu_f(float x) { return x / (1.f + __expf(-x)); }
__device__ __forceinline__ float softplus_f(float x) {
    return fmaxf(x, 0.f) + log1pf(__expf(-fabsf(x)));
}
__device__ __forceinline__ float gelu_f(float x) {
    return 0.5f * x * (1.f + erff(x * 0.70710678118654752440f));
}
__device__ __forceinline__ float wave_sum64(float v) {
#pragma unroll
    for (int m = 32; m > 0; m >>= 1) v += __shfl_xor(v, m, 64);
    return v;
}

// ---------------------------------------------------------------------------
// K1: mamba. grid (256, 12), block 256 = 4 waves. Wave w: c = blockIdx.y,
// b-range [(blockIdx.x*4+w)*8, +8). lane = channel e.
// ---------------------------------------------------------------------------
__global__ __launch_bounds__(256) void k1_mamba(
    const float* __restrict__ x,          // (8192,12,64)
    const float* __restrict__ in_proj_w,  // (12,128,64)
    const float* __restrict__ conv_w,     // (12,64,2)
    const float* __restrict__ conv_b,     // (12,64)
    const float* __restrict__ x_proj_w,   // (12,16,64)
    const float* __restrict__ dt_proj_w,  // (12,64,4)
    const float* __restrict__ dt_proj_b,  // (12,64)
    const float* __restrict__ D_ssm,      // (12,64)
    const float* __restrict__ out_proj_w, // (12,64,64)
    const float* __restrict__ channel_w,  // (12)
    float* __restrict__ s1)               // (8192,12,64) all_out
{
    __shared__ __align__(16) float Xl[4][8][68];  // x rows (residual)
    __shared__ __align__(16) float Cl[4][8][68];  // xc, then y
    __shared__ __align__(16) float Zl[4][8][68];  // silu(z)
    __shared__ __align__(16) float Pr[4][8][16];  // proj

    const int w  = threadIdx.x >> 6;
    const int l  = threadIdx.x & 63;
    const int c  = blockIdx.y;
    const int b0 = (blockIdx.x * 4 + w) * 8;

    const float cw1  = conv_w[c * 128 + 2 * l + 1];
    const float cbl  = conv_b[c * 64 + l];
    const float4 wdt = *(const float4*)(dt_proj_w + c * 256 + 4 * l);
    const float dtbl = dt_proj_b[c * 64 + l];
    const float dsml = D_ssm[c * 64 + l];
    const float cwc  = channel_w[c];

    const float* Wi = in_proj_w + c * (128 * 64);
    const float* Wp = x_proj_w + c * (16 * 64);
    const float* Wo = out_proj_w + c * (64 * 64);

    for (int r = 0; r < 8; ++r)
        Xl[w][r][l] = x[((b0 + r) * 12 + c) * 64 + l];
    __syncthreads();
    PHASE_FENCE();

    // pass A1: xs dot (row l of Wi) -> xc.  acc[8] + wv[8] halves.
    {
        const float4* WiA = (const float4*)(Wi + l * 64);
        float acc[8];
#pragma unroll
        for (int r = 0; r < 8; ++r) acc[r] = 0.f;
#pragma unroll
        for (int half = 0; half < 2; ++half) {
            float4 wv[8];
#pragma unroll
            for (int i = 0; i < 8; ++i) wv[i] = WiA[half * 8 + i];
#pragma unroll
            for (int r = 0; r < 8; ++r) {
                const float4* xr = (const float4*)(&Xl[w][r][0]) + half * 8;
                float a0 = 0.f, a1 = 0.f;
#pragma unroll
                for (int i = 0; i < 8; i += 2) {
                    a0 += dot4f(xr[i], wv[i]);
                    a1 += dot4f(xr[i + 1], wv[i + 1]);
                }
                acc[r] += a0 + a1;
            }
        }
#pragma unroll
        for (int r = 0; r < 8; ++r)
            Cl[w][r][l] = silu_f(acc[r] * cw1 + cbl);
    }
    PHASE_FENCE();
    // pass A2: z dot (row 64+l of Wi) -> silu(z)
    {
        const float4* WiB = (const float4*)(Wi + (64 + l) * 64);
        float acc[8];
#pragma unroll
        for (int r = 0; r < 8; ++r) acc[r] = 0.f;
#pragma unroll
        for (int half = 0; half < 2; ++half) {
            float4 wv[8];
#pragma unroll
            for (int i = 0; i < 8; ++i) wv[i] = WiB[half * 8 + i];
#pragma unroll
            for (int r = 0; r < 8; ++r) {
                const float4* xr = (const float4*)(&Xl[w][r][0]) + half * 8;
                float a0 = 0.f, a1 = 0.f;
#pragma unroll
                for (int i = 0; i < 8; i += 2) {
                    a0 += dot4f(xr[i], wv[i]);
                    a1 += dot4f(xr[i + 1], wv[i + 1]);
                }
                acc[r] += a0 + a1;
            }
        }
#pragma unroll
        for (int r = 0; r < 8; ++r)
            Zl[w][r][l] = silu_f(acc[r]);
    }
    __syncthreads();
    PHASE_FENCE();

    // proj: 128 (r,f) tasks over 64 lanes (2 per lane), wv[8] halves
    {
        const int f = l & 15;
        const float4* wp = (const float4*)(Wp + f * 64);
        float acc[2];
        acc[0] = 0.f; acc[1] = 0.f;
#pragma unroll
        for (int half = 0; half < 2; ++half) {
            float4 wv[8];
#pragma unroll
            for (int i = 0; i < 8; ++i) wv[i] = wp[half * 8 + i];
#pragma unroll
            for (int task = 0; task < 2; ++task) {
                const int r = (l >> 4) + 4 * task;
                const float4* xc4 = (const float4*)(&Cl[w][r][0]) + half * 8;
                float a0 = 0.f, a1 = 0.f;
#pragma unroll
                for (int i = 0; i < 8; i += 2) {
                    a0 += dot4f(xc4[i], wv[i]);
                    a1 += dot4f(xc4[i + 1], wv[i + 1]);
                }
                acc[task] += a0 + a1;
            }
        }
        Pr[w][(l >> 4) + 0][f] = acc[0];
        Pr[w][(l >> 4) + 4][f] = acc[1];
    }
    __syncthreads();
    PHASE_FENCE();

    // y = xc * (dt*bc + D) * silu(z)   (overwrites Cl)
    for (int r = 0; r < 8; ++r) {
        const float* pr = &Pr[w][r][0];
        const float bc = pr[4] * pr[10] + pr[5] * pr[11] + pr[6] * pr[12] +
                         pr[7] * pr[13] + pr[8] * pr[14] + pr[9] * pr[15];
        const float dt = softplus_f(pr[0] * wdt.x + pr[1] * wdt.y +
                                    pr[2] * wdt.z + pr[3] * wdt.w + dtbl);
        Cl[w][r][l] = Cl[w][r][l] * (dt * bc + dsml) * Zl[w][r][l];
    }
    __syncthreads();
    PHASE_FENCE();

    // out-proj + channel weight + residual
    {
        const float4* wo = (const float4*)(Wo + l * 64);
        float acc[8];
#pragma unroll
        for (int r = 0; r < 8; ++r) acc[r] = 0.f;
#pragma unroll
        for (int half = 0; half < 2; ++half) {
            float4 wv[8];
#pragma unroll
            for (int i = 0; i < 8; ++i) wv[i] = wo[half * 8 + i];
#pragma unroll
            for (int r = 0; r < 8; ++r) {
                const float4* yr = (const float4*)(&Cl[w][r][0]) + half * 8;
                float a0 = 0.f, a1 = 0.f;
#pragma unroll
                for (int i = 0; i < 8; i += 2) {
                    a0 += dot4f(yr[i], wv[i]);
                    a1 += dot4f(yr[i + 1], wv[i + 1]);
                }
                acc[r] += a0 + a1;
            }
        }
#pragma unroll
        for (int r = 0; r < 8; ++r)
            s1[((b0 + r) * 12 + c) * 64 + l] = cwc * acc[r] + Xl[w][r][l];
    }
}

// ---------------------------------------------------------------------------
// K2: transformer over C. One wave per b (4 waves/block). lane = token s.
// In-place on io (= d_out). Two-pass softmax, no score array.
// ---------------------------------------------------------------------------
__global__ __launch_bounds__(256) void k2_enc1(
    float* __restrict__ io,           // (8192,12,64) all_out -> x2, in place
    const float* __restrict__ in_w1,  // (36,12)
    const float* __restrict__ in_b1,  // (36)
    const float* __restrict__ ow1,    // (12,12)
    const float* __restrict__ ob1,    // (12)
    const float* __restrict__ n1g, const float* __restrict__ n1b,   // (12)
    const float* __restrict__ m1w1, const float* __restrict__ m1b1, // (24,12),(24)
    const float* __restrict__ m1w2, const float* __restrict__ m1b2) // (12,24),(12)
{
    __shared__ float KV[4][64][25];  // [wave][t][ k0..11 | v0..11 ], pad 25

    const int w = threadIdx.x >> 6;
    const int l = threadIdx.x & 63;
    const int b = blockIdx.x * 4 + w;

    float* io_b = io + b * (12 * 64);

    float tr[12];
#pragma unroll
    for (int i = 0; i < 12; ++i) tr[i] = io_b[i * 64 + l];

    float qreg[12];
#pragma unroll
    for (int e = 0; e < 12; ++e) {
        float acc = in_b1[e];
#pragma unroll
        for (int cc = 0; cc < 12; ++cc) acc += tr[cc] * in_w1[e * 12 + cc];
        qreg[e] = acc * 0.57735026918962576451f;  // 1/sqrt(hd=3)
    }
#pragma clang loop unroll(disable)
    for (int e = 12; e < 36; ++e) {  // rolled: no register-array indexing
        float acc = in_b1[e];
#pragma unroll
        for (int cc = 0; cc < 12; ++cc) acc += tr[cc] * in_w1[e * 12 + cc];
        KV[w][l][e - 12] = acc;
    }
    __syncthreads();
    PHASE_FENCE();

    // attention, two-pass softmax per head (scores recomputed, never stored)
    float orow[12];
#pragma unroll
    for (int h = 0; h < 4; ++h) {
        const float q0 = qreg[3 * h + 0], q1 = qreg[3 * h + 1], q2 = qreg[3 * h + 2];
        float mx = -1e30f;
        for (int t = 0; t < 64; ++t) {
            float s = q0 * KV[w][t][3 * h + 0] + q1 * KV[w][t][3 * h + 1] +
                      q2 * KV[w][t][3 * h + 2];
            mx = fmaxf(mx, s);
        }
        float sum = 0.f, o0 = 0.f, o1 = 0.f, o2 = 0.f;
        for (int t = 0; t < 64; ++t) {
            float s = q0 * KV[w][t][3 * h + 0] + q1 * KV[w][t][3 * h + 1] +
                      q2 * KV[w][t][3 * h + 2];
            float p = __expf(s - mx);
            sum += p;
            o0 += p * KV[w][t][12 + 3 * h + 0];
            o1 += p * KV[w][t][12 + 3 * h + 1];
            o2 += p * KV[w][t][12 + 3 * h + 2];
        }
        const float inv = 1.f / sum;
        orow[3 * h + 0] = o0 * inv;
        orow[3 * h + 1] = o1 * inv;
        orow[3 * h + 2] = o2 * inv;
    }
    PHASE_FENCE();

    // out-proj + residual + LN(12)
    float a[12];
#pragma unroll
    for (int cc = 0; cc < 12; ++cc) {
        float acc = ob1[cc];
#pragma unroll
        for (int e = 0; e < 12; ++e) acc += orow[e] * ow1[cc * 12 + e];
        a[cc] = tr[cc] + acc;
    }
    {
        float mu = 0.f;
#pragma unroll
        for (int i = 0; i < 12; ++i) mu += a[i];
        mu *= (1.f / 12.f);
        float var = 0.f;
#pragma unroll
        for (int i = 0; i < 12; ++i) { float d = a[i] - mu; var += d * d; }
        var *= (1.f / 12.f);
        const float rs = rsqrtf(var + 1e-5f);
#pragma unroll
        for (int i = 0; i < 12; ++i) a[i] = (a[i] - mu) * rs * n1g[i] + n1b[i];
    }
    PHASE_FENCE();

    // MLP 12 -> 24 -> 12 (exact gelu), residual; k rolled (no reg-array by k)
    float a2[12];
#pragma unroll
    for (int i = 0; i < 12; ++i) a2[i] = a[i] + m1b2[i];
#pragma clang loop unroll(disable)
    for (int k = 0; k < 24; ++k) {
        float acc = m1b1[k];
#pragma unroll
        for (int cc = 0; cc < 12; ++cc) acc += a[cc] * m1w1[k * 12 + cc];
        const float hk = gelu_f(acc);
#pragma unroll
        for (int cc = 0; cc < 12; ++cc) a2[cc] += hk * m1w2[cc * 24 + k];
    }
    PHASE_FENCE();

    // second LN(12) with norm1 params -> x2, in place
    {
        float mu = 0.f;
#pragma unroll
        for (int i = 0; i < 12; ++i) mu += a2[i];
        mu *= (1.f / 12.f);
        float var = 0.f;
#pragma unroll
        for (int i = 0; i < 12; ++i) { float d = a2[i] - mu; var += d * d; }
        var *= (1.f / 12.f);
        const float rs = rsqrtf(var + 1e-5f);
#pragma unroll
        for (int cc = 0; cc < 12; ++cc)
            io_b[cc * 64 + l] = (a2[cc] - mu) * rs * n1g[cc] + n1b[cc];
    }
}

// ---------------------------------------------------------------------------
// K3: transformer over D. One wave per b. S=12, E=64, 8 heads, hd=8.
// QKVH buffer stride 196 (16B-aligned rows). O overlays Q cols 0..63 after
// q-preload; H overlays K/V cols 64..191 after attention.
// All matmul phases: acc[12] + wv[8] half-row passes; phase fences + rolled
// k-loops keep cross-phase scheduling (the r6 spill source) impossible.
// ---------------------------------------------------------------------------
__global__ __launch_bounds__(256) void k3_enc2(
    float* __restrict__ io,           // (8192,12,64) x2 -> out, in place
    const float* __restrict__ in_w2,  // (192,64)
    const float* __restrict__ in_b2,  // (192)
    const float* __restrict__ ow2,    // (64,64)
    const float* __restrict__ ob2,    // (64)
    const float* __restrict__ n2g, const float* __restrict__ n2b,   // (64)
    const float* __restrict__ m2w1, const float* __restrict__ m2b1, // (128,64),(128)
    const float* __restrict__ m2w2, const float* __restrict__ m2b2) // (64,128),(64)
{
    __shared__ __align__(16) float Xs[4][12][68];   // 13056 B
    __shared__ __align__(16) float QH[4][12][196];  // 37632 B; total 50688 B

    const int w = threadIdx.x >> 6;
    const int l = threadIdx.x & 63;
    const int b = blockIdx.x * 4 + w;

    float* io_b = io + b * (12 * 64);
#pragma unroll
    for (int t = 0; t < 12; ++t) Xs[w][t][l] = io_b[t * 64 + l];
    __syncthreads();
    PHASE_FENCE();

    // qkv: lane owns cols e = k*64 + l; half-row weight passes; k rolled
#pragma clang loop unroll(disable)
    for (int k = 0; k < 3; ++k) {
        PHASE_FENCE();
        const int e = k * 64 + l;
        const float4* Wrow = (const float4*)(in_w2 + e * 64);
        const float bias = in_b2[e];
        const float scale = (k == 0) ? 0.35355339059327376220f : 1.f;  // hd=8
        float acc[12];
#pragma unroll
        for (int t = 0; t < 12; ++t) acc[t] = 0.f;
#pragma unroll
        for (int half = 0; half < 2; ++half) {
            float4 wv[8];
#pragma unroll
            for (int i = 0; i < 8; ++i) wv[i] = Wrow[half * 8 + i];
#pragma unroll
            for (int t = 0; t < 12; ++t) {
                const float4* xrow = (const float4*)(&Xs[w][t][0]) + half * 8;
                float a0 = 0.f, a1 = 0.f;
#pragma unroll
                for (int i = 0; i < 8; i += 2) {
                    a0 += dot4f(xrow[i], wv[i]);
                    a1 += dot4f(xrow[i + 1], wv[i + 1]);
                }
                acc[t] += a0 + a1;
            }
        }
#pragma unroll
        for (int t = 0; t < 12; ++t)
            QH[w][t][e] = (acc[t] + bias) * scale;
    }
    __syncthreads();
    PHASE_FENCE();

    // attention: 96 (h,s) tasks over 64 lanes x 2 reps. Preload ALL q before
    // any O write (O overlays Q cols 0..63; wave-lockstep makes this safe).
    {
        const int h0 = l / 12, s0 = l - h0 * 12;          // rep0: always valid
        const int r1 = l + 64;
        const int h1 = r1 / 12, s1 = r1 - h1 * 12;        // rep1: valid iff r1<96
        const bool v1 = (r1 < 96);
        float q0v[8], q1v[8];
#pragma unroll
        for (int d = 0; d < 8; ++d) q0v[d] = QH[w][s0][h0 * 8 + d];
#pragma unroll
        for (int d = 0; d < 8; ++d) q1v[d] = QH[w][s1][h1 * 8 + d];  // in-bounds garbage ok

        // rep 0
        {
            float scv[12], mx = -1e30f;
#pragma unroll
            for (int t = 0; t < 12; ++t) {
                float acc = 0.f;
#pragma unroll
                for (int d = 0; d < 8; ++d) acc += q0v[d] * QH[w][t][64 + h0 * 8 + d];
                scv[t] = acc;
                mx = fmaxf(mx, acc);
            }
            float sum = 0.f;
#pragma unroll
            for (int t = 0; t < 12; ++t) { float p = __expf(scv[t] - mx); scv[t] = p; sum += p; }
            const float inv = 1.f / sum;
#pragma unroll
            for (int d = 0; d < 8; ++d) {
                float o = 0.f;
#pragma unroll
                for (int t = 0; t < 12; ++t) o += scv[t] * QH[w][t][128 + h0 * 8 + d];
                QH[w][s0][h0 * 8 + d] = o * inv;   // O overlays Q
            }
        }
        // rep 1
        if (v1) {
            float scv[12], mx = -1e30f;
#pragma unroll
            for (int t = 0; t < 12; ++t) {
                float acc = 0.f;
#pragma unroll
                for (int d = 0; d < 8; ++d) acc += q1v[d] * QH[w][t][64 + h1 * 8 + d];
                scv[t] = acc;
                mx = fmaxf(mx, acc);
            }
            float sum = 0.f;
#pragma unroll
            for (int t = 0; t < 12; ++t) { float p = __expf(scv[t] - mx); scv[t] = p; sum += p; }
            const float inv = 1.f / sum;
#pragma unroll
            for (int d = 0; d < 8; ++d) {
                float o = 0.f;
#pragma unroll
                for (int t = 0; t < 12; ++t) o += scv[t] * QH[w][t][128 + h1 * 8 + d];
                QH[w][s1][h1 * 8 + d] = o * inv;
            }
        }
    }
    __syncthreads();
    PHASE_FENCE();

    // out-proj + residual + LN(64, cross-lane). O rows at QH[w][t][0..63].
    float xa[12];
    {
        const float4* Wrow = (const float4*)(ow2 + l * 64);
        const float bias = ob2[l];
        float acc[12];
#pragma unroll
        for (int t = 0; t < 12; ++t) acc[t] = 0.f;
#pragma unroll
        for (int half = 0; half < 2; ++half) {
            float4 wv[8];
#pragma unroll
            for (int i = 0; i < 8; ++i) wv[i] = Wrow[half * 8 + i];
#pragma unroll
            for (int t = 0; t < 12; ++t) {
                const float4* orow = (const float4*)(&QH[w][t][0]) + half * 8;
                float a0 = 0.f, a1 = 0.f;
#pragma unroll
                for (int i = 0; i < 8; i += 2) {
                    a0 += dot4f(orow[i], wv[i]);
                    a1 += dot4f(orow[i + 1], wv[i + 1]);
                }
                acc[t] += a0 + a1;
            }
        }
        const float gg = n2g[l], bb = n2b[l];
#pragma unroll
        for (int t = 0; t < 12; ++t) {
            float v = Xs[w][t][l] + acc[t] + bias;
            const float mu = wave_sum64(v) * (1.f / 64.f);
            const float dv = v - mu;
            const float var = wave_sum64(dv * dv) * (1.f / 64.f);
            const float vn = dv * rsqrtf(var + 1e-5f) * gg + bb;
            xa[t] = vn;
            Xs[w][t][l] = vn;
        }
    }
    __syncthreads();
    PHASE_FENCE();

    // MLP hidden 64 -> 128 (exact gelu); H overlays K/V: QH[w][t][64+kk]
#pragma clang loop unroll(disable)
    for (int k = 0; k < 2; ++k) {
        PHASE_FENCE();
        const int kk = k * 64 + l;
        const float4* Wrow = (const float4*)(m2w1 + kk * 64);
        const float bias = m2b1[kk];
        float acc[12];
#pragma unroll
        for (int t = 0; t < 12; ++t) acc[t] = 0.f;
#pragma unroll
        for (int half = 0; half < 2; ++half) {
            float4 wv[8];
#pragma unroll
            for (int i = 0; i < 8; ++i) wv[i] = Wrow[half * 8 + i];
#pragma unroll
            for (int t = 0; t < 12; ++t) {
                const float4* xrow = (const float4*)(&Xs[w][t][0]) + half * 8;
                float a0 = 0.f, a1 = 0.f;
#pragma unroll
                for (int i = 0; i < 8; i += 2) {
                    a0 += dot4f(xrow[i], wv[i]);
                    a1 += dot4f(xrow[i + 1], wv[i + 1]);
                }
                acc[t] += a0 + a1;
            }
        }
#pragma unroll
        for (int t = 0; t < 12; ++t)
            QH[w][t][64 + kk] = gelu_f(acc[t] + bias);
    }
    __syncthreads();
    PHASE_FENCE();

    // MLP out 128 -> 64 + residual + final LN(64), write output in place
    float accf[12];
#pragma unroll
    for (int t = 0; t < 12; ++t) accf[t] = m2b2[l];
#pragma clang loop unroll(disable)
    for (int k = 0; k < 2; ++k) {
        PHASE_FENCE();
        const float4* Wrow = (const float4*)(m2w2 + l * 128 + k * 64);
#pragma unroll
        for (int half = 0; half < 2; ++half) {
            float4 wv[8];
#pragma unroll
            for (int i = 0; i < 8; ++i) wv[i] = Wrow[half * 8 + i];
#pragma unroll
            for (int t = 0; t < 12; ++t) {
                const float4* hrow = (const float4*)(&QH[w][t][64 + k * 64]) + half * 8;
                float a0 = 0.f, a1 = 0.f;
#pragma unroll
                for (int i = 0; i < 8; i += 2) {
                    a0 += dot4f(hrow[i], wv[i]);
                    a1 += dot4f(hrow[i + 1], wv[i + 1]);
                }
                accf[t] += a0 + a1;
            }
        }
    }
    PHASE_FENCE();
    {
        const float gg = n2g[l], bb = n2b[l];
#pragma unroll
        for (int t = 0; t < 12; ++t) {
            float v = xa[t] + accf[t];
            const float mu = wave_sum64(v) * (1.f / 64.f);
            const float dv = v - mu;
            const float var = wave_sum64(dv * dv) * (1.f / 64.f);
            io_b[t * 64 + l] = dv * rsqrtf(var + 1e-5f) * gg + bb;
        }
    }
}

// ---------------------------------------------------------------------------
extern "C" void kernel_launch(void* const* d_in, const int* in_sizes, int n_in,
                              void* d_out, int out_size, void* d_ws, size_t ws_size,
                              hipStream_t stream) {
    (void)in_sizes; (void)n_in; (void)d_ws; (void)ws_size; (void)out_size;

    const float* x          = (const float*)d_in[0];
    const float* in_proj_w  = (const float*)d_in[2];
    const float* conv_w     = (const float*)d_in[3];
    const float* conv_b     = (const float*)d_in[4];
    const float* x_proj_w   = (const float*)d_in[5];
    const float* dt_proj_w  = (const float*)d_in[6];
    const float* dt_proj_b  = (const float*)d_in[7];
    const float* D_ssm      = (const float*)d_in[9];
    const float* out_proj_w = (const float*)d_in[10];
    const float* channel_w  = (const float*)d_in[11];
    const float* a1_in_w  = (const float*)d_in[12];
    const float* a1_in_b  = (const float*)d_in[13];
    const float* a1_out_w = (const float*)d_in[14];
    const float* a1_out_b = (const float*)d_in[15];
    const float* a2_in_w  = (const float*)d_in[16];
    const float* a2_in_b  = (const float*)d_in[17];
    const float* a2_out_w = (const float*)d_in[18];
    const float* a2_out_b = (const float*)d_in[19];
    const float* n1g = (const float*)d_in[20];
    const float* n1b = (const float*)d_in[21];
    const float* n2g = (const float*)d_in[22];
    const float* n2b = (const float*)d_in[23];
    const float* m1w1 = (const float*)d_in[24];
    const float* m1b1 = (const float*)d_in[25];
    const float* m1w2 = (const float*)d_in[26];
    const float* m1b2 = (const float*)d_in[27];
    const float* m2w1 = (const float*)d_in[28];
    const float* m2b1 = (const float*)d_in[29];
    const float* m2w2 = (const float*)d_in[30];
    const float* m2b2 = (const float*)d_in[31];

    float* io = (float*)d_out;  // K1 writes all_out; K2, K3 run in place

    k1_mamba<<<dim3(8192 / 32, 12), 256, 0, stream>>>(
        x, in_proj_w, conv_w, conv_b, x_proj_w, dt_proj_w, dt_proj_b,
        D_ssm, out_proj_w, channel_w, io);

    k2_enc1<<<dim3(8192 / 4), 256, 0, stream>>>(
        io, a1_in_w, a1_in_b, a1_out_w, a1_out_b,
        n1g, n1b, m1w1, m1b1, m1w2, m1b2);

    k3_enc2<<<dim3(8192 / 4), 256, 0, stream>>>(
        io, a2_in_w, a2_in_b, a2_out_w, a2_out_b,
        n2g, n2b, m2w1, m2b1, m2w2, m2b2);
}